// Round 8
// baseline (774.730 us; speedup 1.0000x reference)
//
#include <hip/hip_runtime.h>
#include <hip/hip_bf16.h>

typedef float  f32x4  __attribute__((ext_vector_type(4)));
typedef __bf16 bf16x8 __attribute__((ext_vector_type(8)));
typedef short  s16x8  __attribute__((ext_vector_type(8)));
typedef short  s16x4  __attribute__((ext_vector_type(4)));

// fp32 -> bf16 round-to-nearest-even (raw bits in short)
__device__ __forceinline__ short f2b(float f) {
  unsigned u = __builtin_bit_cast(unsigned, f);
  u = (u + 0x7fffu + ((u >> 16) & 1u)) >> 16;
  return (short)u;
}
// bf16 bits -> fp32 (exact)
__device__ __forceinline__ float b2f(short s) {
  unsigned u = ((unsigned)(unsigned short)s) << 16;
  return __builtin_bit_cast(float, u);
}
// 4 fp32 -> 4 bf16 (packed cvt)
__device__ __forceinline__ s16x4 pack4(f32x4 a) {
  union { s16x4 v; __hip_bfloat162 h[2]; } u;
  u.h[0] = __float22bfloat162_rn(make_float2(a[0], a[1]));
  u.h[1] = __float22bfloat162_rn(make_float2(a[2], a[3]));
  return u.v;
}

// W [2][256 c][256 d] fp32  ->  Wt [2][256 d][256 c] bf16 (B-operand friendly)
__global__ void prep_wt(const float* __restrict__ W, short* __restrict__ Wt) {
  int q = blockIdx.x * blockDim.x + threadIdx.x;   // 0..32767, each handles 4 elems
  int mat = q >> 14;
  int rem = q & 16383;
  int d   = rem >> 6;
  int c4  = (rem & 63) << 2;
  const float* src = W + mat * 65536;
  s16x4 o;
  #pragma unroll
  for (int i = 0; i < 4; ++i) o[i] = f2b(src[(c4 + i) * 256 + d]);
  *(s16x4*)&Wt[q << 2] = o;   // flat = mat*65536 + d*256 + c4
}

// R11 (fixed compile: acc[rf][cfr][reg] in phase 1).
//  One big tile per block -- kill the per-item serial chain.
//  R8->R10 measured: TLP doesn't help (R9), amortization helps a little (R10),
//  but per-item latency dominates: 8 items/block x (32 L2 W-loads + 4 barriers)
//  = 32 barriers + 1MB re-read W per block; machine ~75% stalled.
//  Fix: BM=136 rows (8 whole graph-groups) x BN=64 cols x both mats per block,
//  NO item loop. Per block: stage 136x256 -> b1 -> ONE K-loop (W read once,
//  64KB L2) -> b2 -> phase1 -> b3 -> phase2. 3 barriers instead of 32.
//  Per wave: 34 rows (3 rowfrags, padded 48) x 64 cols x 2 mats, acc[3][8]=96
//  VGPR, uncapped. LDS: xs[136][264] bf16 = 71.8KB (epilogue sbuf/gbuf
//  overlaid) + ms[17][64] + aoff -> 77.4KB -> 2 blocks/CU; block A's staging
//  stream overlaps block B's compute (cross-block pipelining).
//  Grid 4096 = 1024 bt x 4 ct; XCD swizzle groups the 4 ct-partners of one bt
//  on the same XCD -> x HBM-fetched once, partners hit L2.
__global__ __launch_bounds__(256)
void fused_mgc(const float* __restrict__ x, const short* __restrict__ Wt,
               const float* __restrict__ M, const float* __restrict__ adj,
               const float* __restrict__ adj2, const float* __restrict__ bias,
               float* __restrict__ out) {
  __shared__ short xs[35904];   // [136][264] bf16 | overlay | sbuf[136][68]+gbuf[136][68]
  __shared__ float ms[1088];    // [17][64] fp32: M slice for this ct
  __shared__ float aoff[289];   // symmetrized A, diagonal zeroed
  __shared__ float diagl[17];   // diag of A

  const int tid  = threadIdx.x;
  const int lane = tid & 63;
  const int wv   = tid >> 6;      // 0..3
  const int m16  = lane & 15;
  const int qd   = lane >> 4;

  // XCD swizzle: phys&7 = XCD; the 4 ct-partners of one bt are consecutive on
  // the same XCD -> x tile HBM-fetched once, partners served by that L2.
  const int phys = blockIdx.x;             // 0..4095
  const int xcd  = phys & 7;
  const int iseq = phys >> 3;              // 0..511
  const int bt   = xcd * 128 + (iseq >> 2);  // 136-row tile: rows bt*136 .. +136
  const int ct   = iseq & 3;                 // 64-col tile

  // ---- preamble (once per block) ----
  for (int idx = tid; idx < 289; idx += 256) {
    int i = idx / 17, j = idx - i * 17;
    float v = 0.5f * ((adj[i*17+j] + adj2[i*17+j]) + (adj[j*17+i] + adj2[j*17+i]));
    aoff[idx] = (i == j) ? 0.0f : v;
    if (i == j) diagl[i] = adj[i*17+i] + adj2[i*17+i];
  }
  for (int q = tid; q < 1088; q += 256) {
    int n = q >> 6, c = q & 63;
    ms[q] = M[n * 256 + ct * 64 + c];
  }

  // ---- stage x tile: 136 rows x 256 k, fp32 -> bf16 LDS (stride 264) ----
  {
    const float* xbase = x + (size_t)bt * 136 * 256;
    const int c4 = (tid & 63) << 2;   // 64 quads = 256 cols; 4 rows per pass
    const int r0 = tid >> 6;          // 0..3
    #pragma unroll
    for (int it = 0; it < 34; ++it) {
      int row = r0 + it * 4;          // 0..135, exact
      f32x4 v = *(const f32x4*)&xbase[row * 256 + c4];
      *(s16x4*)&xs[row * 264 + c4] = pack4(v);
    }
  }

  f32x4 acc[3][8];  // [rowfrag][mat*4+colfrag]
  #pragma unroll
  for (int a = 0; a < 3; ++a)
    #pragma unroll
    for (int b = 0; b < 8; ++b) acc[a][b] = (f32x4)0.0f;

  // B-operand base: row (ct*64 + cfr*16 + m16) of Wt, + mat*65536 + k
  const short* wbase = Wt + (ct * 64 + m16) * 256;

  __syncthreads();   // b1: xs, ms, aoff ready

  // A-row indices; wave owns rows wv*34 .. +33, MFMA pads to 48 (clamp reads)
  int arow[3];
  #pragma unroll
  for (int rf = 0; rf < 3; ++rf) {
    int r = wv * 34 + rf * 16 + m16;
    arow[rf] = (r < 136 ? r : 135) * 264;
  }

  #pragma unroll
  for (int ks = 0; ks < 8; ++ks) {
    const int kq = ks * 32 + qd * 8;
    bf16x8 bfr[8];
    #pragma unroll
    for (int mat = 0; mat < 2; ++mat)
      #pragma unroll
      for (int cfr = 0; cfr < 4; ++cfr) {
        s16x8 w = *(const s16x8*)&wbase[mat * 65536 + cfr * 4096 + kq];
        bfr[mat * 4 + cfr] = __builtin_bit_cast(bf16x8, w);
      }
    #pragma unroll
    for (int rf = 0; rf < 3; ++rf) {
      s16x8 a8 = *(const s16x8*)&xs[arow[rf] + kq];
      bf16x8 af = __builtin_bit_cast(bf16x8, a8);
      #pragma unroll
      for (int b = 0; b < 8; ++b)
        acc[rf][b] = __builtin_amdgcn_mfma_f32_16x16x32_bf16(af, bfr[b], acc[rf][b], 0, 0, 0);
    }
  }
  __syncthreads();   // b2: all waves done reading xs -> overlay writable

  // ---- phase 1: acc -> sbuf/gbuf (overlaid on xs), M/diag applied ----
  short* sbuf = xs;            // [136][68] bf16: diag_n * M * h0
  short* gbuf = xs + 9248;     // [136][68] bf16: M * h1
  #pragma unroll
  for (int rf = 0; rf < 3; ++rf) {
    #pragma unroll
    for (int cfr = 0; cfr < 4; ++cfr) {
      int c = cfr * 16 + m16;        // 0..63
      #pragma unroll
      for (int reg = 0; reg < 4; ++reg) {
        int rl = rf * 16 + qd * 4 + reg;   // row within wave's 48-pad window
        if (rl < 34) {
          int r = wv * 34 + rl;            // 0..135
          int n = r % 17;
          float mv = ms[n * 64 + c];
          sbuf[r * 68 + c] = f2b(diagl[n] * mv * acc[rf][cfr][reg]);
          gbuf[r * 68 + c] = f2b(mv * acc[rf][4 + cfr][reg]);
        }
      }
    }
  }
  __syncthreads();   // b3: sbuf/gbuf ready

  // ---- phase 2: mixing; 8 groups x 64 cols, 2 groups per thread ----
  {
    const int d6 = tid & 63;
    const int gq = tid >> 6;           // 0..3
    const float bi = bias[ct * 64 + d6];
    #pragma unroll
    for (int gg = 0; gg < 2; ++gg) {
      int g = gq * 2 + gg;             // 0..7
      int rbase = g * 17;
      float gr[17];
      #pragma unroll
      for (int j = 0; j < 17; ++j) gr[j] = b2f(gbuf[(rbase + j) * 68 + d6]);
      #pragma unroll
      for (int i = 0; i < 17; ++i) {
        float s = b2f(sbuf[(rbase + i) * 68 + d6]) + bi;
        #pragma unroll
        for (int j = 0; j < 17; ++j) s += aoff[i * 17 + j] * gr[j];
        out[((size_t)(bt * 8 + g) * 17 + i) * 256 + ct * 64 + d6] = s;
      }
    }
  }
}

extern "C" void kernel_launch(void* const* d_in, const int* in_sizes, int n_in,
                              void* d_out, int out_size, void* d_ws, size_t ws_size,
                              hipStream_t stream) {
  const float* x    = (const float*)d_in[0];
  const float* W    = (const float*)d_in[1];
  const float* M    = (const float*)d_in[2];
  const float* adj  = (const float*)d_in[3];
  const float* adj2 = (const float*)d_in[4];
  const float* bias = (const float*)d_in[5];
  float* out = (float*)d_out;
  short* Wt  = (short*)d_ws;   // 262144 B scratch for transposed bf16 weights

  prep_wt<<<128, 256, 0, stream>>>(W, Wt);
  fused_mgc<<<4096, 256, 0, stream>>>(x, Wt, M, adj, adj2, bias, out);
}

// Round 9
// 408.453 us; speedup vs baseline: 1.8967x; 1.8967x over previous
//
#include <hip/hip_runtime.h>
#include <hip/hip_bf16.h>

typedef float  f32x4  __attribute__((ext_vector_type(4)));
typedef __bf16 bf16x8 __attribute__((ext_vector_type(8)));
typedef short  s16x8  __attribute__((ext_vector_type(8)));
typedef short  s16x4  __attribute__((ext_vector_type(4)));

// fp32 -> bf16 round-to-nearest-even (raw bits in short)
__device__ __forceinline__ short f2b(float f) {
  unsigned u = __builtin_bit_cast(unsigned, f);
  u = (u + 0x7fffu + ((u >> 16) & 1u)) >> 16;
  return (short)u;
}
// bf16 bits -> fp32 (exact)
__device__ __forceinline__ float b2f(short s) {
  unsigned u = ((unsigned)(unsigned short)s) << 16;
  return __builtin_bit_cast(float, u);
}
// 4 fp32 -> 4 bf16 (packed cvt)
__device__ __forceinline__ s16x4 pack4(f32x4 a) {
  union { s16x4 v; __hip_bfloat162 h[2]; } u;
  u.h[0] = __float22bfloat162_rn(make_float2(a[0], a[1]));
  u.h[1] = __float22bfloat162_rn(make_float2(a[2], a[3]));
  return u.v;
}

// W [2][256 c][256 d] fp32  ->  Wt [2][256 d][256 c] bf16 (B-operand friendly)
__global__ void prep_wt(const float* __restrict__ W, short* __restrict__ Wt) {
  int q = blockIdx.x * blockDim.x + threadIdx.x;   // 0..32767, each handles 4 elems
  int mat = q >> 14;
  int rem = q & 16383;
  int d   = rem >> 6;
  int c4  = (rem & 63) << 2;
  const float* src = W + mat * 65536;
  s16x4 o;
  #pragma unroll
  for (int i = 0; i < 4; ++i) o[i] = f2b(src[(c4 + i) * 256 + d]);
  *(s16x4*)&Wt[q << 2] = o;   // flat = mat*65536 + d*256 + c4
}

// R12 = R10 skeleton (persistent blocks, 34-row items, reg-prefetch, ms/aoff
// in LDS -- best measured: 194us) with the item pipeline restructured:
//  - DOUBLE-BUFFERED xs (2 x [34][264] bf16): pack(t+1) writes the idle
//    buffer while K(t) reads the live one -> the pack/K WAR barrier is gone.
//    Item = {loads(t+1) || K(t) -> phase1 -> pack(t+1) -> B1 -> phase2 -> B2}:
//    2 barriers/item instead of R10's 4; x-load latency hides under K.
//  - sbuf/gbuf in their OWN region (no overlay tricks): B1 also publishes
//    them; B2 is the WAR fence for the next item's phase1.
//  - phase2 fma TREE (4 partial sums): dep depth ~5 instead of 17.
//  - items=4, grid 2048: 8 block-slots/CU, 2 resident (LDS 63.8KB) -> 4 rounds.
//  - NO launch-bounds cap (R5-R8: caps force spill); LDS is the occupancy
//    limiter so VGPR up to ~250 is harmless. R11 lesson: staging bursts kept
//    at 9 loads, per-wave fragments at acc[3][4]+bfr[4].
__global__ __launch_bounds__(256)
void fused_mgc(const float* __restrict__ x, const short* __restrict__ Wt,
               const float* __restrict__ M, const float* __restrict__ adj,
               const float* __restrict__ adj2, const float* __restrict__ bias,
               float* __restrict__ out) {
  __shared__ short xs0[8976];   // [34][264] bf16, buffer 0
  __shared__ short xs1[8976];   // [34][264] bf16, buffer 1
  __shared__ short sbuf[4488];  // [34][132] bf16: diag_n * M * h0
  __shared__ short gbuf[4488];  // [34][132] bf16: M * h1
  __shared__ float ms[2176];    // [17][128] fp32: M slice for this ct
  __shared__ float aoff[289];   // symmetrized A, diagonal zeroed
  __shared__ float diagl[17];   // diag of A

  const int tid  = threadIdx.x;
  const int lane = tid & 63;
  const int wv   = tid >> 6;
  const int m16  = lane & 15;
  const int qd   = lane >> 4;

  // XCD swizzle: phys&7 = XCD; ct0/ct1 partners of the same bt-range are
  // consecutive on one XCD -> x tiles shared via that XCD's L2.
  const int phys   = blockIdx.x;            // 0..2047
  const int xcd    = phys & 7;
  const int iseq   = phys >> 3;             // 0..255
  const int ct     = iseq & 1;              // col tile (128 d), fixed per block
  const int btbase = (xcd * 128 + (iseq >> 1)) * 4;   // 4 consecutive 34-row tiles

  const int c4 = (tid & 63) << 2;   // col quad for staging
  const int r0 = tid >> 6;          // 0..3

  // ---- prologue ----
  f32x4 xp[9];
  {
    const float* xb = x + (size_t)btbase * 34 * 256;
    #pragma unroll
    for (int it = 0; it < 9; ++it) {
      int row = r0 + it * 4;
      if (row < 34) xp[it] = *(const f32x4*)&xb[row * 256 + c4];
    }
  }
  for (int idx = tid; idx < 289; idx += 256) {
    int i = idx / 17, j = idx - i * 17;
    float v = 0.5f * ((adj[i*17+j] + adj2[i*17+j]) + (adj[j*17+i] + adj2[j*17+i]));
    aoff[idx] = (i == j) ? 0.0f : v;
    if (i == j) diagl[i] = adj[i*17+i] + adj2[i*17+i];
  }
  for (int q = tid; q < 544; q += 256) {
    int n = q >> 5, cq = (q & 31) << 2;
    *(f32x4*)&ms[n * 128 + cq] = *(const f32x4*)&M[n * 256 + ct * 128 + cq];
  }
  // pack tile 0 -> xs0
  #pragma unroll
  for (int it = 0; it < 9; ++it) {
    int row = r0 + it * 4;
    if (row < 34) *(s16x4*)&xs0[row * 264 + c4] = pack4(xp[it]);
  }

  const short* wbase = Wt + (ct * 128 + wv * 32 + m16) * 256;  // + mat*65536 + cf*4096

  int arow[3];
  #pragma unroll
  for (int rf = 0; rf < 3; ++rf) {
    int r = rf * 16 + m16;
    arow[rf] = (r < 34 ? r : 33) * 264;   // clamp: pad rows re-read row 33
  }

  const int d7   = tid & 127;
  const int g    = tid >> 7;            // batch-group within item (0..1)
  const float bi = bias[ct * 128 + d7];

  __syncthreads();   // xs0, ms, aoff ready

  const short* xsp = xs0;   // live buffer (K reads)
  short*       xsn = xs1;   // idle buffer (pack writes)

  for (int t = 0; t < 4; ++t) {
    const int bt = btbase + t;

    // ---- issue loads for tile t+1 (land under the K-loop) ----
    if (t < 3) {
      const float* xb = x + (size_t)(bt + 1) * 34 * 256;
      #pragma unroll
      for (int it = 0; it < 9; ++it) {
        int row = r0 + it * 4;
        if (row < 34) xp[it] = *(const f32x4*)&xb[row * 256 + c4];
      }
    }

    // ---- K-loop on live buffer ----
    f32x4 acc[3][4];  // [rowfrag][mat*2+colfrag]
    #pragma unroll
    for (int a = 0; a < 3; ++a)
      #pragma unroll
      for (int b = 0; b < 4; ++b) acc[a][b] = (f32x4)0.0f;

    #pragma unroll
    for (int ks = 0; ks < 8; ++ks) {
      const int kq = ks * 32 + qd * 8;
      bf16x8 bfr[4];
      #pragma unroll
      for (int mc = 0; mc < 4; ++mc) {
        int mat = mc >> 1, cf = mc & 1;
        s16x8 w = *(const s16x8*)&wbase[mat * 65536 + cf * 4096 + kq];
        bfr[mc] = __builtin_bit_cast(bf16x8, w);
      }
      #pragma unroll
      for (int rf = 0; rf < 3; ++rf) {
        s16x8 a8 = *(const s16x8*)&xsp[arow[rf] + kq];
        bf16x8 af = __builtin_bit_cast(bf16x8, a8);
        #pragma unroll
        for (int mc = 0; mc < 4; ++mc)
          acc[rf][mc] = __builtin_amdgcn_mfma_f32_16x16x32_bf16(af, bfr[mc], acc[rf][mc], 0, 0, 0);
      }
    }

    // ---- phase 1: acc -> sbuf/gbuf (own region; B2 of prev item fenced WAR) ----
    #pragma unroll
    for (int rf = 0; rf < 3; ++rf) {
      #pragma unroll
      for (int cf = 0; cf < 2; ++cf) {
        int c = wv * 32 + cf * 16 + m16;
        #pragma unroll
        for (int reg = 0; reg < 4; ++reg) {
          int r = rf * 16 + qd * 4 + reg;
          if (r < 34) {
            int n = r - (r >= 17 ? 17 : 0);
            float mv = ms[n * 128 + c];
            sbuf[r * 132 + c] = f2b(diagl[n] * mv * acc[rf][cf][reg]);
            gbuf[r * 132 + c] = f2b(mv * acc[rf][2 + cf][reg]);
          }
        }
      }
    }

    // ---- pack tile t+1 into idle buffer (no reader until after B2) ----
    if (t < 3) {
      #pragma unroll
      for (int it = 0; it < 9; ++it) {
        int row = r0 + it * 4;
        if (row < 34) *(s16x4*)&xsn[row * 264 + c4] = pack4(xp[it]);
      }
    }

    __syncthreads();   // B1: sbuf/gbuf published; xsn packed

    // ---- phase 2: mixing with 4-way fma tree; store out ----
    {
      int rbase = g * 17;
      float gr[17];
      #pragma unroll
      for (int j = 0; j < 17; ++j) gr[j] = b2f(gbuf[(rbase + j) * 132 + d7]);
      #pragma unroll
      for (int i = 0; i < 17; ++i) {
        const float* ar = &aoff[i * 17];
        float s0 = ar[0] * gr[0] + b2f(sbuf[(rbase + i) * 132 + d7]) + bi;
        float s1 = ar[1] * gr[1];
        float s2 = ar[2] * gr[2];
        float s3 = ar[3] * gr[3];
        #pragma unroll
        for (int j = 4; j < 16; j += 4) {
          s0 += ar[j]     * gr[j];
          s1 += ar[j + 1] * gr[j + 1];
          s2 += ar[j + 2] * gr[j + 2];
          s3 += ar[j + 3] * gr[j + 3];
        }
        s0 += ar[16] * gr[16];
        out[((size_t)(bt * 2 + g) * 17 + i) * 256 + ct * 128 + d7] =
            (s0 + s1) + (s2 + s3);
      }
    }

    __syncthreads();   // B2: phase2 readers done (sbuf/gbuf free); xsn consumable

    // swap buffers
    const short* tmp = xsp; xsp = xsn; xsn = (short*)tmp;
  }
}

extern "C" void kernel_launch(void* const* d_in, const int* in_sizes, int n_in,
                              void* d_out, int out_size, void* d_ws, size_t ws_size,
                              hipStream_t stream) {
  const float* x    = (const float*)d_in[0];
  const float* W    = (const float*)d_in[1];
  const float* M    = (const float*)d_in[2];
  const float* adj  = (const float*)d_in[3];
  const float* adj2 = (const float*)d_in[4];
  const float* bias = (const float*)d_in[5];
  float* out = (float*)d_out;
  short* Wt  = (short*)d_ws;   // 262144 B scratch for transposed bf16 weights

  prep_wt<<<128, 256, 0, stream>>>(W, Wt);
  fused_mgc<<<2048, 256, 0, stream>>>(x, Wt, M, adj, adj2, bias, out);
}